// Round 3
// baseline (27231.656 us; speedup 1.0000x reference)
//
#include <hip/hip_runtime.h>
#include <math.h>

// L=1024, B=24, D=512.
// Pipeline: tk=tanh(v.Wp_^T) [full]; per 128-i chunk: tq, fused
// scores+softmax+context (attn), Gi = C.w_ih^T+b_ih, then a PERSISTENT GRU
// kernel doing 128 sequential steps with an in-kernel device-scope barrier
// (grid=256 blocks, w_hh fragments pinned in registers across steps).

// ---------------------------------------------------------------------------
// GEMM: out[m][n] = post(A[m][:] . B[n][:] (+ bias[n])), A: MxK rm, B: NxK rm.
__launch_bounds__(256, 2)
__global__ void gemm_abt_kernel(const float* __restrict__ A, const float* __restrict__ B,
                                float* __restrict__ out, int K, int N,
                                const float* __restrict__ bias, int do_tanh) {
  __shared__ __align__(16) float As[16][136];
  __shared__ __align__(16) float Bs[16][136];
  const int m0 = blockIdx.y * 128, n0 = blockIdx.x * 128;
  const int tid = threadIdx.x;
  const int tm = (tid & 15) * 8, tn = (tid >> 4) * 8;
  const int srow = tid & 127, scol = (tid >> 7) * 8;
  const float* Ap = A + (size_t)(m0 + srow) * K + scol;
  const float* Bp = B + (size_t)(n0 + srow) * K + scol;
  float acc[8][8] = {{0.f}};
  for (int k0 = 0; k0 < K; k0 += 16) {
    const float4 a0 = *(const float4*)(Ap + k0);
    const float4 a1 = *(const float4*)(Ap + k0 + 4);
    const float4 b0 = *(const float4*)(Bp + k0);
    const float4 b1 = *(const float4*)(Bp + k0 + 4);
    __syncthreads();
    As[scol + 0][srow] = a0.x; As[scol + 1][srow] = a0.y;
    As[scol + 2][srow] = a0.z; As[scol + 3][srow] = a0.w;
    As[scol + 4][srow] = a1.x; As[scol + 5][srow] = a1.y;
    As[scol + 6][srow] = a1.z; As[scol + 7][srow] = a1.w;
    Bs[scol + 0][srow] = b0.x; Bs[scol + 1][srow] = b0.y;
    Bs[scol + 2][srow] = b0.z; Bs[scol + 3][srow] = b0.w;
    Bs[scol + 4][srow] = b1.x; Bs[scol + 5][srow] = b1.y;
    Bs[scol + 6][srow] = b1.z; Bs[scol + 7][srow] = b1.w;
    __syncthreads();
#pragma unroll
    for (int kk = 0; kk < 16; ++kk) {
      const float4 av0 = *(const float4*)&As[kk][tm];
      const float4 av1 = *(const float4*)&As[kk][tm + 4];
      const float4 bv0 = *(const float4*)&Bs[kk][tn];
      const float4 bv1 = *(const float4*)&Bs[kk][tn + 4];
      const float ar[8] = {av0.x, av0.y, av0.z, av0.w, av1.x, av1.y, av1.z, av1.w};
      const float br[8] = {bv0.x, bv0.y, bv0.z, bv0.w, bv1.x, bv1.y, bv1.z, bv1.w};
#pragma unroll
      for (int r = 0; r < 8; ++r)
#pragma unroll
        for (int c = 0; c < 8; ++c)
          acc[r][c] = fmaf(ar[r], br[c], acc[r][c]);
    }
  }
#pragma unroll
  for (int r = 0; r < 8; ++r) {
    float* o = out + (size_t)(m0 + tm + r) * N + n0 + tn;
#pragma unroll
    for (int c = 0; c < 8; ++c) {
      float val = acc[r][c];
      if (bias) val += bias[n0 + tn + c];
      if (do_tanh) val = tanhf(val);
      o[c] = val;
    }
  }
}

// ---------------------------------------------------------------------------
// Fused scores + softmax + context for one i-chunk.
// tanh(q+k) = u + w(1-u^2)/(1+uw); sum_h V*u is const in l -> dropped
// (softmax-invariant). V'[i][h] = V[h]*(1-u^2) lives in registers.
__launch_bounds__(256, 3)
__global__ void attn_kernel(const float* __restrict__ tq, const float* __restrict__ tk,
                            const float* __restrict__ Vv, const float* __restrict__ v,
                            float* __restrict__ Cout) {
  const int b = blockIdx.y;
  const int it = blockIdx.x;           // i-tile within chunk (il = it*4+ii)
  const int tid = threadIdx.x;
  const int wave = tid >> 6, lane = tid & 63;
  const int h8 = lane * 8;
  __shared__ __align__(16) float sm[4][1024];
  __shared__ __align__(16) float red[4][4][512];
  __shared__ float inv_s[4];

  float q[4][8], vp[4][8];
  {
    const float* vvp = Vv + (size_t)b * 512 + h8;
    const float4 v0 = *(const float4*)vvp;
    const float4 v1 = *(const float4*)(vvp + 4);
    const float vv[8] = {v0.x, v0.y, v0.z, v0.w, v1.x, v1.y, v1.z, v1.w};
#pragma unroll
    for (int ii = 0; ii < 4; ++ii) {
      const float* qp = tq + ((size_t)(it * 4 + ii) * 24 + b) * 512 + h8;
      const float4 q0 = *(const float4*)qp;
      const float4 q1 = *(const float4*)(qp + 4);
      q[ii][0] = q0.x; q[ii][1] = q0.y; q[ii][2] = q0.z; q[ii][3] = q0.w;
      q[ii][4] = q1.x; q[ii][5] = q1.y; q[ii][6] = q1.z; q[ii][7] = q1.w;
#pragma unroll
      for (int j = 0; j < 8; ++j)
        vp[ii][j] = vv[j] * (1.0f - q[ii][j] * q[ii][j]);
    }
  }

  for (int l = wave; l < 1024; l += 4) {
    const float* kp = tk + ((size_t)l * 24 + b) * 512 + h8;
    const float4 k0 = *(const float4*)kp;
    const float4 k1 = *(const float4*)(kp + 4);
    const float kkv[8] = {k0.x, k0.y, k0.z, k0.w, k1.x, k1.y, k1.z, k1.w};
    float acc0 = 0.f, acc1 = 0.f, acc2 = 0.f, acc3 = 0.f;
#pragma unroll
    for (int j = 0; j < 8; ++j) {
      const float w = kkv[j];
      // acc += V' * w / (1 + u*w)
      acc0 = fmaf(vp[0][j] * w, __builtin_amdgcn_rcpf(fmaf(q[0][j], w, 1.0f)), acc0);
      acc1 = fmaf(vp[1][j] * w, __builtin_amdgcn_rcpf(fmaf(q[1][j], w, 1.0f)), acc1);
      acc2 = fmaf(vp[2][j] * w, __builtin_amdgcn_rcpf(fmaf(q[2][j], w, 1.0f)), acc2);
      acc3 = fmaf(vp[3][j] * w, __builtin_amdgcn_rcpf(fmaf(q[3][j], w, 1.0f)), acc3);
    }
#pragma unroll
    for (int mask = 32; mask; mask >>= 1) {
      acc0 += __shfl_xor(acc0, mask, 64);
      acc1 += __shfl_xor(acc1, mask, 64);
      acc2 += __shfl_xor(acc2, mask, 64);
      acc3 += __shfl_xor(acc3, mask, 64);
    }
    if (lane == 0) {
      sm[0][l] = acc0; sm[1][l] = acc1; sm[2][l] = acc2; sm[3][l] = acc3;
    }
  }
  __syncthreads();

  // softmax of row `wave` in place (exp only; normalization folded into output)
  {
    float* row = sm[wave];
    float m = -1e30f;
    for (int t = lane; t < 1024; t += 64) m = fmaxf(m, row[t]);
#pragma unroll
    for (int mask = 32; mask; mask >>= 1) m = fmaxf(m, __shfl_xor(m, mask, 64));
    float s = 0.f;
    for (int t = lane; t < 1024; t += 64) {
      const float e = __expf(row[t] - m);
      row[t] = e;
      s += e;
    }
#pragma unroll
    for (int mask = 32; mask; mask >>= 1) s += __shfl_xor(s, mask, 64);
    if (lane == 0) inv_s[wave] = 1.0f / s;
  }
  __syncthreads();

  // context: wave w covers l in [256w, 256w+256), lane owns d-slice h8
  float ca[4][8] = {{0.f}};
  const int l0 = wave * 256;
  for (int l = l0; l < l0 + 256; ++l) {
    const float* vrow = v + ((size_t)l * 24 + b) * 512 + h8;
    const float4 x0 = *(const float4*)vrow;
    const float4 x1 = *(const float4*)(vrow + 4);
    const float a0 = sm[0][l], a1 = sm[1][l], a2 = sm[2][l], a3 = sm[3][l];
    const float xv[8] = {x0.x, x0.y, x0.z, x0.w, x1.x, x1.y, x1.z, x1.w};
#pragma unroll
    for (int j = 0; j < 8; ++j) {
      ca[0][j] = fmaf(a0, xv[j], ca[0][j]);
      ca[1][j] = fmaf(a1, xv[j], ca[1][j]);
      ca[2][j] = fmaf(a2, xv[j], ca[2][j]);
      ca[3][j] = fmaf(a3, xv[j], ca[3][j]);
    }
  }
#pragma unroll
  for (int ii = 0; ii < 4; ++ii) {
    *(float4*)&red[wave][ii][h8]     = make_float4(ca[ii][0], ca[ii][1], ca[ii][2], ca[ii][3]);
    *(float4*)&red[wave][ii][h8 + 4] = make_float4(ca[ii][4], ca[ii][5], ca[ii][6], ca[ii][7]);
  }
  __syncthreads();
  {
    const int ii = tid >> 6;
    const int d0 = (tid & 63) * 8;
    float4 s0 = *(const float4*)&red[0][ii][d0];
    float4 s1 = *(const float4*)&red[0][ii][d0 + 4];
#pragma unroll
    for (int w = 1; w < 4; ++w) {
      const float4 r0 = *(const float4*)&red[w][ii][d0];
      const float4 r1 = *(const float4*)&red[w][ii][d0 + 4];
      s0.x += r0.x; s0.y += r0.y; s0.z += r0.z; s0.w += r0.w;
      s1.x += r1.x; s1.y += r1.y; s1.z += r1.z; s1.w += r1.w;
    }
    const float inv = inv_s[ii];
    s0.x *= inv; s0.y *= inv; s0.z *= inv; s0.w *= inv;
    s1.x *= inv; s1.y *= inv; s1.z *= inv; s1.w *= inv;
    float* o = Cout + ((size_t)(it * 4 + ii) * 24 + b) * 512 + d0;
    *(float4*)o = s0;
    *(float4*)(o + 4) = s1;
  }
}

// ---------------------------------------------------------------------------
// Persistent GRU: 128 steps per launch. Grid 256 = 32 d-slices (wb) x 8
// b-groups (bg, 3 batches). Thread (dd = t&15, kc = t>>4) holds
// w_hh[{r,z,n} x (wb*16+dd)][kc*32 .. +32) in 96 VGPRs across all steps.
// h exchanged via double-buffered global; device-scope generation barrier.
__launch_bounds__(256, 2)
__global__ void gru_persist_kernel(const float* __restrict__ Gi_c, const float* __restrict__ w_hh,
                                   const float* __restrict__ b_hh, const float* __restrict__ h0,
                                   float* __restrict__ hb0, float* __restrict__ hb1,
                                   float* __restrict__ out, unsigned* __restrict__ bar,
                                   int gstep0) {
  const int wb = blockIdx.x & 31;
  const int bg = blockIdx.x >> 5;
  const int t = threadIdx.x;
  const int dd = t & 15, kc = t >> 4;
  const int k0 = kc * 32;
  const int dglob = wb * 16 + dd;
  unsigned* cnt = bar;
  unsigned* gen = bar + 1;

  __shared__ float red[9][16][20];
  __shared__ float ghs[9][16];

  // pin w fragments in registers for the whole launch
  float wreg[3][32];
#pragma unroll
  for (int g = 0; g < 3; ++g) {
    const float* wr = w_hh + (size_t)(g * 512 + dglob) * 512 + k0;
#pragma unroll
    for (int j = 0; j < 32; j += 4) {
      const float4 wv = *(const float4*)(wr + j);
      wreg[g][j] = wv.x; wreg[g][j + 1] = wv.y; wreg[g][j + 2] = wv.z; wreg[g][j + 3] = wv.w;
    }
  }
  const int gb = t >> 4;                    // reduce-phase row id (valid < 9)
  float bias = 0.f;
  if (gb < 9) bias = b_hh[(gb / 3) * 512 + dglob];

  for (int il = 0; il < 128; ++il) {
    const int gs = gstep0 + il;
    const float* hprev = (gs == 0) ? h0 : ((gs & 1) ? hb0 : hb1);

    // prefetch gate-combine inputs (independent of this step's barrier wait)
    float gir = 0.f, giz = 0.f, gin = 0.f, hold = 0.f;
    if (t < 48) {
      const int bglob = bg * 3 + (t >> 4);
      const float* gi = Gi_c + ((size_t)il * 24 + bglob) * 1536;
      gir = gi[dglob]; giz = gi[512 + dglob]; gin = gi[1024 + dglob];
      hold = hprev[(size_t)bglob * 512 + dglob];
    }

    // partial dots: 3 batches x 3 gates over k in [k0, k0+32)
    float pr[3][3];
#pragma unroll
    for (int b = 0; b < 3; ++b) {
      const float* hp = hprev + (size_t)(bg * 3 + b) * 512 + k0;
      float4 h4[8];
#pragma unroll
      for (int j = 0; j < 8; ++j) h4[j] = *(const float4*)(hp + j * 4);
      float a0 = 0.f, a1 = 0.f, a2 = 0.f;
#pragma unroll
      for (int j = 0; j < 8; ++j) {
        const float4 hv = h4[j];
        a0 = fmaf(hv.x, wreg[0][j*4], fmaf(hv.y, wreg[0][j*4+1], fmaf(hv.z, wreg[0][j*4+2], fmaf(hv.w, wreg[0][j*4+3], a0))));
        a1 = fmaf(hv.x, wreg[1][j*4], fmaf(hv.y, wreg[1][j*4+1], fmaf(hv.z, wreg[1][j*4+2], fmaf(hv.w, wreg[1][j*4+3], a1))));
        a2 = fmaf(hv.x, wreg[2][j*4], fmaf(hv.y, wreg[2][j*4+1], fmaf(hv.z, wreg[2][j*4+2], fmaf(hv.w, wreg[2][j*4+3], a2))));
      }
      pr[b][0] = a0; pr[b][1] = a1; pr[b][2] = a2;
    }
#pragma unroll
    for (int b = 0; b < 3; ++b)
#pragma unroll
      for (int g = 0; g < 3; ++g)
        red[g * 3 + b][dd][kc] = pr[b][g];
    __syncthreads();

    if (gb < 9) {
      const float* rr = &red[gb][dd][0];
      float s = 0.f;
#pragma unroll
      for (int qq = 0; qq < 16; ++qq) s += rr[qq];
      ghs[gb][dd] = s + bias;
    }
    __syncthreads();

    if (t < 48) {
      const int b = t >> 4;
      const float ghr = ghs[b][dd];
      const float ghz = ghs[3 + b][dd];
      const float ghn = ghs[6 + b][dd];
      const float r = 1.0f / (1.0f + __expf(-(gir + ghr)));
      const float z = 1.0f / (1.0f + __expf(-(giz + ghz)));
      const float n = tanhf(gin + r * ghn);
      const float hn = (1.0f - z) * n + z * hold;
      const int bglob = bg * 3 + b;
      float* hnx = (gs & 1) ? hb1 : hb0;
      hnx[(size_t)bglob * 512 + dglob] = hn;
      out[((size_t)gs * 24 + bglob) * 512 + dglob] = hn;
    }
    __syncthreads();

    // device-scope generation barrier (grid.sync pattern)
    if (t == 0) {
      __threadfence();
      const unsigned old = __hip_atomic_fetch_add(cnt, 1u, __ATOMIC_ACQ_REL, __HIP_MEMORY_SCOPE_AGENT);
      if (old == 255u) {
        __hip_atomic_store(cnt, 0u, __ATOMIC_RELAXED, __HIP_MEMORY_SCOPE_AGENT);
        __hip_atomic_fetch_add(gen, 1u, __ATOMIC_RELEASE, __HIP_MEMORY_SCOPE_AGENT);
      } else {
        while (__hip_atomic_load(gen, __ATOMIC_ACQUIRE, __HIP_MEMORY_SCOPE_AGENT) < (unsigned)(il + 1)) {}
      }
    }
    __syncthreads();
  }
}

// ---------------------------------------------------------------------------
extern "C" void kernel_launch(void* const* d_in, const int* in_sizes, int n_in,
                              void* d_out, int out_size, void* d_ws, size_t ws_size,
                              hipStream_t stream) {
  (void)in_sizes; (void)n_in; (void)out_size;
  const float* v    = (const float*)d_in[0];
  const float* h0   = (const float*)d_in[1];
  const float* Vv   = (const float*)d_in[2];
  const float* Wp   = (const float*)d_in[3];
  const float* Wp_  = (const float*)d_in[4];
  const float* w_ih = (const float*)d_in[5];
  const float* w_hh = (const float*)d_in[6];
  const float* b_ih = (const float*)d_in[7];
  const float* b_hh = (const float*)d_in[8];
  float* out = (float*)d_out;

  // workspace layout; full-tq path needs ~120.1 MiB, chunked ~78.1 MiB
  const bool full_tq = ws_size >= (size_t)125927500;
  float* ws   = (float*)d_ws;
  float* tk   = ws;                                  // 12,582,912 fl
  float* tqF  = tk + (size_t)12582912;               // full path only
  float* tq_c = tk + (size_t)12582912;               // chunked path only
  float* C_c  = full_tq ? (tqF + (size_t)12582912) : (tq_c + (size_t)1572864);
  float* Gi_c = C_c + (size_t)1572864;               // 4,718,592 fl
  float* hb0  = Gi_c + (size_t)4718592;              // 12,288 fl
  float* hb1  = hb0 + (size_t)12288;                 // 12,288 fl
  unsigned* bar = (unsigned*)(hb1 + (size_t)12288);  // 2 x u32

  // key projection (full): tk = tanh(v . Wp_^T)
  gemm_abt_kernel<<<dim3(4, 192), 256, 0, stream>>>(v, Wp_, tk, 512, 512, nullptr, 1);
  if (full_tq)
    gemm_abt_kernel<<<dim3(4, 192), 256, 0, stream>>>(v, Wp, tqF, 512, 512, nullptr, 1);

  for (int c = 0; c < 8; ++c) {
    const float* v_chunk = v + (size_t)c * 128 * 24 * 512;
    const float* tq_use;
    if (full_tq) {
      tq_use = tqF + (size_t)c * 128 * 24 * 512;
    } else {
      gemm_abt_kernel<<<dim3(4, 24), 256, 0, stream>>>(v_chunk, Wp, tq_c, 512, 512, nullptr, 1);
      tq_use = tq_c;
    }
    attn_kernel<<<dim3(32, 24), 256, 0, stream>>>(tq_use, tk, Vv, v, C_c);
    gemm_abt_kernel<<<dim3(12, 24), 256, 0, stream>>>(C_c, w_ih, Gi_c, 512, 1536, b_ih, 0);
    hipMemsetAsync(bar, 0, 2 * sizeof(unsigned), stream);
    gru_persist_kernel<<<256, 256, 0, stream>>>(Gi_c, w_hh, b_hh, h0, hb0, hb1,
                                                out, bar, c * 128);
  }
}

// Round 4
// 12119.823 us; speedup vs baseline: 2.2469x; 2.2469x over previous
//
#include <hip/hip_runtime.h>
#include <math.h>

// L=1024, B=24, D=512.
// Pipeline: tk=tanh(v.Wp_^T) [full]; per 128-i chunk: tq, fused
// scores+softmax+context (attn), Gi = C.w_ih^T+b_ih, then a persistent GRU
// kernel doing 128 steps. GRU sync: per-BATCH flag handshake (8 blocks/batch),
// not a device-wide barrier — R3 counters showed the 256-block central atomic
// barrier cost ~22 us/step (VALUBusy 2.2%).

#define GRU_FLAG_STRIDE 32  // u32s => 128 B per flag line

// ---------------------------------------------------------------------------
// GEMM: out[m][n] = post(A[m][:] . B[n][:] (+ bias[n])), A: MxK rm, B: NxK rm.
__launch_bounds__(256, 2)
__global__ void gemm_abt_kernel(const float* __restrict__ A, const float* __restrict__ B,
                                float* __restrict__ out, int K, int N,
                                const float* __restrict__ bias, int do_tanh) {
  __shared__ __align__(16) float As[16][136];
  __shared__ __align__(16) float Bs[16][136];
  const int m0 = blockIdx.y * 128, n0 = blockIdx.x * 128;
  const int tid = threadIdx.x;
  const int tm = (tid & 15) * 8, tn = (tid >> 4) * 8;
  const int srow = tid & 127, scol = (tid >> 7) * 8;
  const float* Ap = A + (size_t)(m0 + srow) * K + scol;
  const float* Bp = B + (size_t)(n0 + srow) * K + scol;
  float acc[8][8] = {{0.f}};
  for (int k0 = 0; k0 < K; k0 += 16) {
    const float4 a0 = *(const float4*)(Ap + k0);
    const float4 a1 = *(const float4*)(Ap + k0 + 4);
    const float4 b0 = *(const float4*)(Bp + k0);
    const float4 b1 = *(const float4*)(Bp + k0 + 4);
    __syncthreads();
    As[scol + 0][srow] = a0.x; As[scol + 1][srow] = a0.y;
    As[scol + 2][srow] = a0.z; As[scol + 3][srow] = a0.w;
    As[scol + 4][srow] = a1.x; As[scol + 5][srow] = a1.y;
    As[scol + 6][srow] = a1.z; As[scol + 7][srow] = a1.w;
    Bs[scol + 0][srow] = b0.x; Bs[scol + 1][srow] = b0.y;
    Bs[scol + 2][srow] = b0.z; Bs[scol + 3][srow] = b0.w;
    Bs[scol + 4][srow] = b1.x; Bs[scol + 5][srow] = b1.y;
    Bs[scol + 6][srow] = b1.z; Bs[scol + 7][srow] = b1.w;
    __syncthreads();
#pragma unroll
    for (int kk = 0; kk < 16; ++kk) {
      const float4 av0 = *(const float4*)&As[kk][tm];
      const float4 av1 = *(const float4*)&As[kk][tm + 4];
      const float4 bv0 = *(const float4*)&Bs[kk][tn];
      const float4 bv1 = *(const float4*)&Bs[kk][tn + 4];
      const float ar[8] = {av0.x, av0.y, av0.z, av0.w, av1.x, av1.y, av1.z, av1.w};
      const float br[8] = {bv0.x, bv0.y, bv0.z, bv0.w, bv1.x, bv1.y, bv1.z, bv1.w};
#pragma unroll
      for (int r = 0; r < 8; ++r)
#pragma unroll
        for (int c = 0; c < 8; ++c)
          acc[r][c] = fmaf(ar[r], br[c], acc[r][c]);
    }
  }
#pragma unroll
  for (int r = 0; r < 8; ++r) {
    float* o = out + (size_t)(m0 + tm + r) * N + n0 + tn;
#pragma unroll
    for (int c = 0; c < 8; ++c) {
      float val = acc[r][c];
      if (bias) val += bias[n0 + tn + c];
      if (do_tanh) val = tanhf(val);
      o[c] = val;
    }
  }
}

// ---------------------------------------------------------------------------
// Fused scores + softmax + context for one i-chunk.
// tanh(q+k) = u + w(1-u^2)/(1+uw); sum_h V*u is const in l -> dropped
// (softmax-invariant). V'[i][h] = V[h]*(1-u^2) lives in registers.
__launch_bounds__(256, 3)
__global__ void attn_kernel(const float* __restrict__ tq, const float* __restrict__ tk,
                            const float* __restrict__ Vv, const float* __restrict__ v,
                            float* __restrict__ Cout) {
  const int b = blockIdx.y;
  const int it = blockIdx.x;           // i-tile within chunk (il = it*4+ii)
  const int tid = threadIdx.x;
  const int wave = tid >> 6, lane = tid & 63;
  const int h8 = lane * 8;
  __shared__ __align__(16) float sm[4][1024];
  __shared__ __align__(16) float red[4][4][512];
  __shared__ float inv_s[4];

  float q[4][8], vp[4][8];
  {
    const float* vvp = Vv + (size_t)b * 512 + h8;
    const float4 v0 = *(const float4*)vvp;
    const float4 v1 = *(const float4*)(vvp + 4);
    const float vv[8] = {v0.x, v0.y, v0.z, v0.w, v1.x, v1.y, v1.z, v1.w};
#pragma unroll
    for (int ii = 0; ii < 4; ++ii) {
      const float* qp = tq + ((size_t)(it * 4 + ii) * 24 + b) * 512 + h8;
      const float4 q0 = *(const float4*)qp;
      const float4 q1 = *(const float4*)(qp + 4);
      q[ii][0] = q0.x; q[ii][1] = q0.y; q[ii][2] = q0.z; q[ii][3] = q0.w;
      q[ii][4] = q1.x; q[ii][5] = q1.y; q[ii][6] = q1.z; q[ii][7] = q1.w;
#pragma unroll
      for (int j = 0; j < 8; ++j)
        vp[ii][j] = vv[j] * (1.0f - q[ii][j] * q[ii][j]);
    }
  }

  for (int l = wave; l < 1024; l += 4) {
    const float* kp = tk + ((size_t)l * 24 + b) * 512 + h8;
    const float4 k0 = *(const float4*)kp;
    const float4 k1 = *(const float4*)(kp + 4);
    const float kkv[8] = {k0.x, k0.y, k0.z, k0.w, k1.x, k1.y, k1.z, k1.w};
    float acc0 = 0.f, acc1 = 0.f, acc2 = 0.f, acc3 = 0.f;
#pragma unroll
    for (int j = 0; j < 8; ++j) {
      const float w = kkv[j];
      acc0 = fmaf(vp[0][j] * w, __builtin_amdgcn_rcpf(fmaf(q[0][j], w, 1.0f)), acc0);
      acc1 = fmaf(vp[1][j] * w, __builtin_amdgcn_rcpf(fmaf(q[1][j], w, 1.0f)), acc1);
      acc2 = fmaf(vp[2][j] * w, __builtin_amdgcn_rcpf(fmaf(q[2][j], w, 1.0f)), acc2);
      acc3 = fmaf(vp[3][j] * w, __builtin_amdgcn_rcpf(fmaf(q[3][j], w, 1.0f)), acc3);
    }
#pragma unroll
    for (int mask = 32; mask; mask >>= 1) {
      acc0 += __shfl_xor(acc0, mask, 64);
      acc1 += __shfl_xor(acc1, mask, 64);
      acc2 += __shfl_xor(acc2, mask, 64);
      acc3 += __shfl_xor(acc3, mask, 64);
    }
    if (lane == 0) {
      sm[0][l] = acc0; sm[1][l] = acc1; sm[2][l] = acc2; sm[3][l] = acc3;
    }
  }
  __syncthreads();

  // softmax of row `wave` in place (exp only; normalization folded into output)
  {
    float* row = sm[wave];
    float m = -1e30f;
    for (int t = lane; t < 1024; t += 64) m = fmaxf(m, row[t]);
#pragma unroll
    for (int mask = 32; mask; mask >>= 1) m = fmaxf(m, __shfl_xor(m, mask, 64));
    float s = 0.f;
    for (int t = lane; t < 1024; t += 64) {
      const float e = __expf(row[t] - m);
      row[t] = e;
      s += e;
    }
#pragma unroll
    for (int mask = 32; mask; mask >>= 1) s += __shfl_xor(s, mask, 64);
    if (lane == 0) inv_s[wave] = 1.0f / s;
  }
  __syncthreads();

  // context: wave w covers l in [256w, 256w+256), lane owns d-slice h8
  float ca[4][8] = {{0.f}};
  const int l0 = wave * 256;
  for (int l = l0; l < l0 + 256; ++l) {
    const float* vrow = v + ((size_t)l * 24 + b) * 512 + h8;
    const float4 x0 = *(const float4*)vrow;
    const float4 x1 = *(const float4*)(vrow + 4);
    const float a0 = sm[0][l], a1 = sm[1][l], a2 = sm[2][l], a3 = sm[3][l];
    const float xv[8] = {x0.x, x0.y, x0.z, x0.w, x1.x, x1.y, x1.z, x1.w};
#pragma unroll
    for (int j = 0; j < 8; ++j) {
      ca[0][j] = fmaf(a0, xv[j], ca[0][j]);
      ca[1][j] = fmaf(a1, xv[j], ca[1][j]);
      ca[2][j] = fmaf(a2, xv[j], ca[2][j]);
      ca[3][j] = fmaf(a3, xv[j], ca[3][j]);
    }
  }
#pragma unroll
  for (int ii = 0; ii < 4; ++ii) {
    *(float4*)&red[wave][ii][h8]     = make_float4(ca[ii][0], ca[ii][1], ca[ii][2], ca[ii][3]);
    *(float4*)&red[wave][ii][h8 + 4] = make_float4(ca[ii][4], ca[ii][5], ca[ii][6], ca[ii][7]);
  }
  __syncthreads();
  {
    const int ii = tid >> 6;
    const int d0 = (tid & 63) * 8;
    float4 s0 = *(const float4*)&red[0][ii][d0];
    float4 s1 = *(const float4*)&red[0][ii][d0 + 4];
#pragma unroll
    for (int w = 1; w < 4; ++w) {
      const float4 r0 = *(const float4*)&red[w][ii][d0];
      const float4 r1 = *(const float4*)&red[w][ii][d0 + 4];
      s0.x += r0.x; s0.y += r0.y; s0.z += r0.z; s0.w += r0.w;
      s1.x += r1.x; s1.y += r1.y; s1.z += r1.z; s1.w += r1.w;
    }
    const float inv = inv_s[ii];
    s0.x *= inv; s0.y *= inv; s0.z *= inv; s0.w *= inv;
    s1.x *= inv; s1.y *= inv; s1.z *= inv; s1.w *= inv;
    float* o = Cout + ((size_t)(it * 4 + ii) * 24 + b) * 512 + d0;
    *(float4*)o = s0;
    *(float4*)(o + 4) = s1;
  }
}

// ---------------------------------------------------------------------------
// Persistent GRU, per-batch sync domain. Grid 192: blockIdx = sl*24 + bg
// (bg = batch 0..23, sl = d-slice 0..7). A batch's 8 blocks are congruent
// mod 8 -> likely same XCD (perf heuristic only). 512 threads:
// d_loc = t&63, kc = t>>6; thread pins w_hh[{r,z,n} x (sl*64+d_loc)][kc*64..+64)
// = 192 floats in VGPRs for the whole launch. h double-buffered in global;
// readiness via per-(batch,slice) monotone step flags (release/acquire, agent).
__launch_bounds__(512, 2)
__global__ void gru_persist_kernel(const float* __restrict__ Gi_c, const float* __restrict__ w_hh,
                                   const float* __restrict__ b_hh, const float* __restrict__ h0,
                                   float* __restrict__ hb0, float* __restrict__ hb1,
                                   float* __restrict__ out, unsigned* __restrict__ flags,
                                   int gstep0) {
  const int bg = blockIdx.x % 24;
  const int sl = blockIdx.x / 24;
  const int t = threadIdx.x;
  const int d_loc = t & 63;
  const int kc = t >> 6;
  const int dglob = sl * 64 + d_loc;

  __shared__ __align__(16) float h_lds[512];
  __shared__ float red[3][64][9];
  __shared__ float ghs[3][64];

  // pin weight fragments in registers
  float wreg[3][64];
#pragma unroll
  for (int g = 0; g < 3; ++g) {
    const float* wr = w_hh + (size_t)(g * 512 + dglob) * 512 + kc * 64;
#pragma unroll
    for (int j = 0; j < 64; j += 4) {
      const float4 wv = *(const float4*)(wr + j);
      wreg[g][j] = wv.x; wreg[g][j + 1] = wv.y; wreg[g][j + 2] = wv.z; wreg[g][j + 3] = wv.w;
    }
  }
  const float bias_r = b_hh[dglob];
  const float bias_z = b_hh[512 + dglob];
  const float bias_n = b_hh[1024 + dglob];

  unsigned* myflags = flags + (size_t)bg * 8 * GRU_FLAG_STRIDE;

  for (int il = 0; il < 128; ++il) {
    const int gs = gstep0 + il;
    // wait until h_{gs} is fully published by all 8 slices of this batch
    if (t < 8) {
      while (__hip_atomic_load(&myflags[t * GRU_FLAG_STRIDE], __ATOMIC_ACQUIRE,
                               __HIP_MEMORY_SCOPE_AGENT) < (unsigned)gs) {
        __builtin_amdgcn_s_sleep(2);
      }
    }
    __syncthreads();

    // stage h_{gs} (this batch) into LDS
    const float* hsrc = (gs == 0) ? (h0 + (size_t)bg * 512)
                                  : (((gs & 1) ? hb0 : hb1) + (size_t)bg * 512);
    if (t < 128) *(float4*)&h_lds[t * 4] = *(const float4*)(hsrc + t * 4);

    // hoist gi loads (consumed after the reduce)
    float gir = 0.f, giz = 0.f, gin = 0.f;
    if (t < 64) {
      const float* gi = Gi_c + ((size_t)il * 24 + bg) * 1536;
      gir = gi[dglob]; giz = gi[512 + dglob]; gin = gi[1024 + dglob];
    }
    __syncthreads();

    // partial dots over k in [kc*64, kc*64+64); LDS reads are wave-uniform
    float a0 = 0.f, a1 = 0.f, a2 = 0.f;
#pragma unroll
    for (int j = 0; j < 64; j += 4) {
      const float4 hv = *(const float4*)&h_lds[kc * 64 + j];
      a0 = fmaf(hv.x, wreg[0][j], fmaf(hv.y, wreg[0][j+1], fmaf(hv.z, wreg[0][j+2], fmaf(hv.w, wreg[0][j+3], a0))));
      a1 = fmaf(hv.x, wreg[1][j], fmaf(hv.y, wreg[1][j+1], fmaf(hv.z, wreg[1][j+2], fmaf(hv.w, wreg[1][j+3], a1))));
      a2 = fmaf(hv.x, wreg[2][j], fmaf(hv.y, wreg[2][j+1], fmaf(hv.z, wreg[2][j+2], fmaf(hv.w, wreg[2][j+3], a2))));
    }
    red[0][d_loc][kc] = a0;
    red[1][d_loc][kc] = a1;
    red[2][d_loc][kc] = a2;
    __syncthreads();

    if (t < 192) {
      const int g = t >> 6, d = t & 63;
      const float* rr = red[g][d];
      float s = ((rr[0] + rr[1]) + (rr[2] + rr[3])) + ((rr[4] + rr[5]) + (rr[6] + rr[7]));
      ghs[g][d] = s;
    }
    __syncthreads();

    if (t < 64) {
      const float hold = h_lds[dglob];
      const float r = 1.0f / (1.0f + __expf(-(gir + ghs[0][t] + bias_r)));
      const float z = 1.0f / (1.0f + __expf(-(giz + ghs[1][t] + bias_z)));
      const float n = tanhf(gin + r * (ghs[2][t] + bias_n));
      const float hn = (1.0f - z) * n + z * hold;
      float* hdst = ((gs & 1) ? hb1 : hb0) + (size_t)bg * 512;
      hdst[dglob] = hn;
      out[((size_t)gs * 24 + bg) * 512 + dglob] = hn;
    }
    __syncthreads();   // each wave drains its stores (vmcnt) at this barrier

    if (t == 0) {
      __threadfence();  // push dirty lines to device coherence point
      __hip_atomic_store(&myflags[sl * GRU_FLAG_STRIDE], (unsigned)(gs + 1),
                         __ATOMIC_RELEASE, __HIP_MEMORY_SCOPE_AGENT);
    }
  }
}

// ---------------------------------------------------------------------------
extern "C" void kernel_launch(void* const* d_in, const int* in_sizes, int n_in,
                              void* d_out, int out_size, void* d_ws, size_t ws_size,
                              hipStream_t stream) {
  (void)in_sizes; (void)n_in; (void)out_size;
  const float* v    = (const float*)d_in[0];
  const float* h0   = (const float*)d_in[1];
  const float* Vv   = (const float*)d_in[2];
  const float* Wp   = (const float*)d_in[3];
  const float* Wp_  = (const float*)d_in[4];
  const float* w_ih = (const float*)d_in[5];
  const float* w_hh = (const float*)d_in[6];
  const float* b_ih = (const float*)d_in[7];
  const float* b_hh = (const float*)d_in[8];
  float* out = (float*)d_out;

  // workspace layout; full-tq path needs ~120.2 MiB, chunked ~78.2 MiB
  const bool full_tq = ws_size >= (size_t)125927500;
  float* ws   = (float*)d_ws;
  float* tk   = ws;                                  // 12,582,912 fl
  float* tqF  = tk + (size_t)12582912;               // full path only
  float* tq_c = tk + (size_t)12582912;               // chunked path only
  float* C_c  = full_tq ? (tqF + (size_t)12582912) : (tq_c + (size_t)1572864);
  float* Gi_c = C_c + (size_t)1572864;               // 4,718,592 fl
  float* hb0  = Gi_c + (size_t)4718592;              // 12,288 fl
  float* hb1  = hb0 + (size_t)12288;                 // 12,288 fl
  unsigned* flags = (unsigned*)(hb1 + (size_t)12288); // 24*8*32 u32 = 24 KiB

  // step flags are monotone across the 8 GRU launches: one reset per call
  hipMemsetAsync(flags, 0, (size_t)24 * 8 * GRU_FLAG_STRIDE * sizeof(unsigned), stream);

  // key projection (full): tk = tanh(v . Wp_^T)
  gemm_abt_kernel<<<dim3(4, 192), 256, 0, stream>>>(v, Wp_, tk, 512, 512, nullptr, 1);
  if (full_tq)
    gemm_abt_kernel<<<dim3(4, 192), 256, 0, stream>>>(v, Wp, tqF, 512, 512, nullptr, 1);

  for (int c = 0; c < 8; ++c) {
    const float* v_chunk = v + (size_t)c * 128 * 24 * 512;
    const float* tq_use;
    if (full_tq) {
      tq_use = tqF + (size_t)c * 128 * 24 * 512;
    } else {
      gemm_abt_kernel<<<dim3(4, 24), 256, 0, stream>>>(v_chunk, Wp, tq_c, 512, 512, nullptr, 1);
      tq_use = tq_c;
    }
    attn_kernel<<<dim3(32, 24), 256, 0, stream>>>(tq_use, tk, Vv, v, C_c);
    gemm_abt_kernel<<<dim3(12, 24), 256, 0, stream>>>(C_c, w_ih, Gi_c, 512, 1536, b_ih, 0);
    gru_persist_kernel<<<192, 512, 0, stream>>>(Gi_c, w_hh, b_hh, h0, hb0, hb1,
                                                out, flags, c * 128);
  }
}

// Round 5
// 7898.372 us; speedup vs baseline: 3.4478x; 1.5345x over previous
//
#include <hip/hip_runtime.h>
#include <math.h>

// L=1024, B=24, D=512.
// Pipeline: tk=tanh(v.Wp_^T) [full]; per 128-i chunk: tq, fused
// scores+softmax+context (attn), Gi = C.w_ih^T+b_ih, then a persistent GRU
// kernel doing 128 steps with per-batch flag handshakes.
// R4 lesson: launch_bounds(512,2) gave 128 regs/lane -> 192-float wreg spilled
// (VGPR_Count=120, ~200KB scratch reread/block/step). Now (512,1) = 256 regs.
// R4 lesson 2: __threadfence = buffer_wbl2 (full dirty-L2 flush) per step;
// replaced by agent-scope (sc1) atomic h stores/loads + release flag.

#define GRU_FLAG_STRIDE 32  // u32s => 128 B per flag line

// ---------------------------------------------------------------------------
// GEMM: out[m][n] = post(A[m][:] . B[n][:] (+ bias[n])), A: MxK rm, B: NxK rm.
__launch_bounds__(256, 2)
__global__ void gemm_abt_kernel(const float* __restrict__ A, const float* __restrict__ B,
                                float* __restrict__ out, int K, int N,
                                const float* __restrict__ bias, int do_tanh) {
  __shared__ __align__(16) float As[16][136];
  __shared__ __align__(16) float Bs[16][136];
  const int m0 = blockIdx.y * 128, n0 = blockIdx.x * 128;
  const int tid = threadIdx.x;
  const int tm = (tid & 15) * 8, tn = (tid >> 4) * 8;
  const int srow = tid & 127, scol = (tid >> 7) * 8;
  const float* Ap = A + (size_t)(m0 + srow) * K + scol;
  const float* Bp = B + (size_t)(n0 + srow) * K + scol;
  float acc[8][8] = {{0.f}};
  for (int k0 = 0; k0 < K; k0 += 16) {
    const float4 a0 = *(const float4*)(Ap + k0);
    const float4 a1 = *(const float4*)(Ap + k0 + 4);
    const float4 b0 = *(const float4*)(Bp + k0);
    const float4 b1 = *(const float4*)(Bp + k0 + 4);
    __syncthreads();
    As[scol + 0][srow] = a0.x; As[scol + 1][srow] = a0.y;
    As[scol + 2][srow] = a0.z; As[scol + 3][srow] = a0.w;
    As[scol + 4][srow] = a1.x; As[scol + 5][srow] = a1.y;
    As[scol + 6][srow] = a1.z; As[scol + 7][srow] = a1.w;
    Bs[scol + 0][srow] = b0.x; Bs[scol + 1][srow] = b0.y;
    Bs[scol + 2][srow] = b0.z; Bs[scol + 3][srow] = b0.w;
    Bs[scol + 4][srow] = b1.x; Bs[scol + 5][srow] = b1.y;
    Bs[scol + 6][srow] = b1.z; Bs[scol + 7][srow] = b1.w;
    __syncthreads();
#pragma unroll
    for (int kk = 0; kk < 16; ++kk) {
      const float4 av0 = *(const float4*)&As[kk][tm];
      const float4 av1 = *(const float4*)&As[kk][tm + 4];
      const float4 bv0 = *(const float4*)&Bs[kk][tn];
      const float4 bv1 = *(const float4*)&Bs[kk][tn + 4];
      const float ar[8] = {av0.x, av0.y, av0.z, av0.w, av1.x, av1.y, av1.z, av1.w};
      const float br[8] = {bv0.x, bv0.y, bv0.z, bv0.w, bv1.x, bv1.y, bv1.z, bv1.w};
#pragma unroll
      for (int r = 0; r < 8; ++r)
#pragma unroll
        for (int c = 0; c < 8; ++c)
          acc[r][c] = fmaf(ar[r], br[c], acc[r][c]);
    }
  }
#pragma unroll
  for (int r = 0; r < 8; ++r) {
    float* o = out + (size_t)(m0 + tm + r) * N + n0 + tn;
#pragma unroll
    for (int c = 0; c < 8; ++c) {
      float val = acc[r][c];
      if (bias) val += bias[n0 + tn + c];
      if (do_tanh) val = tanhf(val);
      o[c] = val;
    }
  }
}

// ---------------------------------------------------------------------------
// Fused scores + softmax + context for one i-chunk.
// tanh(q+k) = u + w(1-u^2)/(1+uw); sum_h V*u is const in l -> dropped
// (softmax-invariant). V'[i][h] = V[h]*(1-u^2) lives in registers.
__launch_bounds__(256, 3)
__global__ void attn_kernel(const float* __restrict__ tq, const float* __restrict__ tk,
                            const float* __restrict__ Vv, const float* __restrict__ v,
                            float* __restrict__ Cout) {
  const int b = blockIdx.y;
  const int it = blockIdx.x;           // i-tile within chunk (il = it*4+ii)
  const int tid = threadIdx.x;
  const int wave = tid >> 6, lane = tid & 63;
  const int h8 = lane * 8;
  __shared__ __align__(16) float sm[4][1024];
  __shared__ __align__(16) float red[4][4][512];
  __shared__ float inv_s[4];

  float q[4][8], vp[4][8];
  {
    const float* vvp = Vv + (size_t)b * 512 + h8;
    const float4 v0 = *(const float4*)vvp;
    const float4 v1 = *(const float4*)(vvp + 4);
    const float vv[8] = {v0.x, v0.y, v0.z, v0.w, v1.x, v1.y, v1.z, v1.w};
#pragma unroll
    for (int ii = 0; ii < 4; ++ii) {
      const float* qp = tq + ((size_t)(it * 4 + ii) * 24 + b) * 512 + h8;
      const float4 q0 = *(const float4*)qp;
      const float4 q1 = *(const float4*)(qp + 4);
      q[ii][0] = q0.x; q[ii][1] = q0.y; q[ii][2] = q0.z; q[ii][3] = q0.w;
      q[ii][4] = q1.x; q[ii][5] = q1.y; q[ii][6] = q1.z; q[ii][7] = q1.w;
#pragma unroll
      for (int j = 0; j < 8; ++j)
        vp[ii][j] = vv[j] * (1.0f - q[ii][j] * q[ii][j]);
    }
  }

  for (int l = wave; l < 1024; l += 4) {
    const float* kp = tk + ((size_t)l * 24 + b) * 512 + h8;
    const float4 k0 = *(const float4*)kp;
    const float4 k1 = *(const float4*)(kp + 4);
    const float kkv[8] = {k0.x, k0.y, k0.z, k0.w, k1.x, k1.y, k1.z, k1.w};
    float acc0 = 0.f, acc1 = 0.f, acc2 = 0.f, acc3 = 0.f;
#pragma unroll
    for (int j = 0; j < 8; ++j) {
      const float w = kkv[j];
      acc0 = fmaf(vp[0][j] * w, __builtin_amdgcn_rcpf(fmaf(q[0][j], w, 1.0f)), acc0);
      acc1 = fmaf(vp[1][j] * w, __builtin_amdgcn_rcpf(fmaf(q[1][j], w, 1.0f)), acc1);
      acc2 = fmaf(vp[2][j] * w, __builtin_amdgcn_rcpf(fmaf(q[2][j], w, 1.0f)), acc2);
      acc3 = fmaf(vp[3][j] * w, __builtin_amdgcn_rcpf(fmaf(q[3][j], w, 1.0f)), acc3);
    }
#pragma unroll
    for (int mask = 32; mask; mask >>= 1) {
      acc0 += __shfl_xor(acc0, mask, 64);
      acc1 += __shfl_xor(acc1, mask, 64);
      acc2 += __shfl_xor(acc2, mask, 64);
      acc3 += __shfl_xor(acc3, mask, 64);
    }
    if (lane == 0) {
      sm[0][l] = acc0; sm[1][l] = acc1; sm[2][l] = acc2; sm[3][l] = acc3;
    }
  }
  __syncthreads();

  // softmax of row `wave` in place (exp only; normalization folded into output)
  {
    float* row = sm[wave];
    float m = -1e30f;
    for (int t = lane; t < 1024; t += 64) m = fmaxf(m, row[t]);
#pragma unroll
    for (int mask = 32; mask; mask >>= 1) m = fmaxf(m, __shfl_xor(m, mask, 64));
    float s = 0.f;
    for (int t = lane; t < 1024; t += 64) {
      const float e = __expf(row[t] - m);
      row[t] = e;
      s += e;
    }
#pragma unroll
    for (int mask = 32; mask; mask >>= 1) s += __shfl_xor(s, mask, 64);
    if (lane == 0) inv_s[wave] = 1.0f / s;
  }
  __syncthreads();

  // context: wave w covers l in [256w, 256w+256), lane owns d-slice h8
  float ca[4][8] = {{0.f}};
  const int l0 = wave * 256;
  for (int l = l0; l < l0 + 256; ++l) {
    const float* vrow = v + ((size_t)l * 24 + b) * 512 + h8;
    const float4 x0 = *(const float4*)vrow;
    const float4 x1 = *(const float4*)(vrow + 4);
    const float a0 = sm[0][l], a1 = sm[1][l], a2 = sm[2][l], a3 = sm[3][l];
    const float xv[8] = {x0.x, x0.y, x0.z, x0.w, x1.x, x1.y, x1.z, x1.w};
#pragma unroll
    for (int j = 0; j < 8; ++j) {
      ca[0][j] = fmaf(a0, xv[j], ca[0][j]);
      ca[1][j] = fmaf(a1, xv[j], ca[1][j]);
      ca[2][j] = fmaf(a2, xv[j], ca[2][j]);
      ca[3][j] = fmaf(a3, xv[j], ca[3][j]);
    }
  }
#pragma unroll
  for (int ii = 0; ii < 4; ++ii) {
    *(float4*)&red[wave][ii][h8]     = make_float4(ca[ii][0], ca[ii][1], ca[ii][2], ca[ii][3]);
    *(float4*)&red[wave][ii][h8 + 4] = make_float4(ca[ii][4], ca[ii][5], ca[ii][6], ca[ii][7]);
  }
  __syncthreads();
  {
    const int ii = tid >> 6;
    const int d0 = (tid & 63) * 8;
    float4 s0 = *(const float4*)&red[0][ii][d0];
    float4 s1 = *(const float4*)&red[0][ii][d0 + 4];
#pragma unroll
    for (int w = 1; w < 4; ++w) {
      const float4 r0 = *(const float4*)&red[w][ii][d0];
      const float4 r1 = *(const float4*)&red[w][ii][d0 + 4];
      s0.x += r0.x; s0.y += r0.y; s0.z += r0.z; s0.w += r0.w;
      s1.x += r1.x; s1.y += r1.y; s1.z += r1.z; s1.w += r1.w;
    }
    const float inv = inv_s[ii];
    s0.x *= inv; s0.y *= inv; s0.z *= inv; s0.w *= inv;
    s1.x *= inv; s1.y *= inv; s1.z *= inv; s1.w *= inv;
    float* o = Cout + ((size_t)(it * 4 + ii) * 24 + b) * 512 + d0;
    *(float4*)o = s0;
    *(float4*)(o + 4) = s1;
  }
}

// ---------------------------------------------------------------------------
// Persistent GRU, per-batch sync domain. Grid 192: blockIdx = sl*24 + bg.
// 512 threads, 1 block/CU (launch_bounds(512,1) -> 256 regs/lane so the
// 192-float weight fragment is truly register-resident).
// h exchange: agent-scope (sc1) relaxed atomic stores/loads (bypass L1/L2,
// no buffer_wbl2) + release/relaxed monotone step flags.
__launch_bounds__(512, 1)
__global__ void gru_persist_kernel(const float* __restrict__ Gi_c, const float* __restrict__ w_hh,
                                   const float* __restrict__ b_hh, const float* __restrict__ h0,
                                   float* __restrict__ hb0, float* __restrict__ hb1,
                                   float* __restrict__ out, unsigned* __restrict__ flags,
                                   int gstep0) {
  const int bg = blockIdx.x % 24;
  const int sl = blockIdx.x / 24;
  const int t = threadIdx.x;
  const int d_loc = t & 63;
  const int kc = t >> 6;
  const int dglob = sl * 64 + d_loc;

  __shared__ __align__(16) float h_lds[512];
  __shared__ float red[3][64][9];
  __shared__ float ghs[3][64];

  // pin weight fragments in registers (192 floats/thread; fits at 1 blk/CU)
  float wreg[3][64];
#pragma unroll
  for (int g = 0; g < 3; ++g) {
    const float* wr = w_hh + (size_t)(g * 512 + dglob) * 512 + kc * 64;
#pragma unroll
    for (int j = 0; j < 64; j += 4) {
      const float4 wv = *(const float4*)(wr + j);
      wreg[g][j] = wv.x; wreg[g][j + 1] = wv.y; wreg[g][j + 2] = wv.z; wreg[g][j + 3] = wv.w;
    }
  }
  const float bias_r = b_hh[dglob];
  const float bias_z = b_hh[512 + dglob];
  const float bias_n = b_hh[1024 + dglob];

  unsigned* myflags = flags + (size_t)bg * 8 * GRU_FLAG_STRIDE;

  for (int il = 0; il < 128; ++il) {
    const int gs = gstep0 + il;
    // wait until h_{gs} is published by all 8 slices of this batch.
    // relaxed agent loads (sc1): no buffer_inv; h itself is read via sc1 too.
    if (t < 8) {
      while (__hip_atomic_load(&myflags[t * GRU_FLAG_STRIDE], __ATOMIC_RELAXED,
                               __HIP_MEMORY_SCOPE_AGENT) < (unsigned)gs) {
        __builtin_amdgcn_s_sleep(2);
      }
    }
    __syncthreads();

    // stage h_{gs} into LDS via 8B agent-scope loads (bypass L1/L2)
    const float* hsrc = (gs == 0) ? (h0 + (size_t)bg * 512)
                                  : (((gs & 1) ? hb0 : hb1) + (size_t)bg * 512);
    if (t < 256) {
      const unsigned long long u = __hip_atomic_load(
          (const unsigned long long*)hsrc + t, __ATOMIC_RELAXED, __HIP_MEMORY_SCOPE_AGENT);
      union { unsigned long long u; float f[2]; } cv; cv.u = u;
      h_lds[2 * t] = cv.f[0];
      h_lds[2 * t + 1] = cv.f[1];
    }

    // hoist gi loads (consumed after the reduce)
    float gir = 0.f, giz = 0.f, gin = 0.f;
    if (t < 64) {
      const float* gi = Gi_c + ((size_t)il * 24 + bg) * 1536;
      gir = gi[dglob]; giz = gi[512 + dglob]; gin = gi[1024 + dglob];
    }
    __syncthreads();

    // partial dots over k in [kc*64, kc*64+64); 6 independent FMA chains
    float a0 = 0.f, a1 = 0.f, a2 = 0.f, b0 = 0.f, b1 = 0.f, b2 = 0.f;
#pragma unroll
    for (int j = 0; j < 64; j += 8) {
      const float4 h1 = *(const float4*)&h_lds[kc * 64 + j];
      const float4 h2 = *(const float4*)&h_lds[kc * 64 + j + 4];
      a0 = fmaf(h1.x, wreg[0][j], fmaf(h1.y, wreg[0][j+1], fmaf(h1.z, wreg[0][j+2], fmaf(h1.w, wreg[0][j+3], a0))));
      b0 = fmaf(h2.x, wreg[0][j+4], fmaf(h2.y, wreg[0][j+5], fmaf(h2.z, wreg[0][j+6], fmaf(h2.w, wreg[0][j+7], b0))));
      a1 = fmaf(h1.x, wreg[1][j], fmaf(h1.y, wreg[1][j+1], fmaf(h1.z, wreg[1][j+2], fmaf(h1.w, wreg[1][j+3], a1))));
      b1 = fmaf(h2.x, wreg[1][j+4], fmaf(h2.y, wreg[1][j+5], fmaf(h2.z, wreg[1][j+6], fmaf(h2.w, wreg[1][j+7], b1))));
      a2 = fmaf(h1.x, wreg[2][j], fmaf(h1.y, wreg[2][j+1], fmaf(h1.z, wreg[2][j+2], fmaf(h1.w, wreg[2][j+3], a2))));
      b2 = fmaf(h2.x, wreg[2][j+4], fmaf(h2.y, wreg[2][j+5], fmaf(h2.z, wreg[2][j+6], fmaf(h2.w, wreg[2][j+7], b2))));
    }
    red[0][d_loc][kc] = a0 + b0;
    red[1][d_loc][kc] = a1 + b1;
    red[2][d_loc][kc] = a2 + b2;
    __syncthreads();

    if (t < 192) {
      const int g = t >> 6, d = t & 63;
      const float* rr = red[g][d];
      ghs[g][d] = ((rr[0] + rr[1]) + (rr[2] + rr[3])) + ((rr[4] + rr[5]) + (rr[6] + rr[7]));
    }
    __syncthreads();

    if (t < 64) {
      const float hold = h_lds[dglob];
      const float r = 1.0f / (1.0f + __expf(-(gir + ghs[0][t] + bias_r)));
      const float z = 1.0f / (1.0f + __expf(-(giz + ghs[1][t] + bias_z)));
      const float n = tanhf(gin + r * (ghs[2][t] + bias_n));
      const float hn = (1.0f - z) * n + z * hold;
      float* hdst = ((gs & 1) ? hb1 : hb0) + (size_t)bg * 512;
      // agent-scope store: lands at device coherence point, no wbl2 needed
      __hip_atomic_store(&hdst[dglob], hn, __ATOMIC_RELAXED, __HIP_MEMORY_SCOPE_AGENT);
      out[((size_t)gs * 24 + bg) * 512 + dglob] = hn;
      if (t == 0) {
        // producer is this single wave: RELEASE waits our vmcnt, orders h
        // stores before the flag becomes visible.
        __hip_atomic_store(&myflags[sl * GRU_FLAG_STRIDE], (unsigned)(gs + 1),
                           __ATOMIC_RELEASE, __HIP_MEMORY_SCOPE_AGENT);
      }
    }
    __syncthreads();
  }
}

// ---------------------------------------------------------------------------
extern "C" void kernel_launch(void* const* d_in, const int* in_sizes, int n_in,
                              void* d_out, int out_size, void* d_ws, size_t ws_size,
                              hipStream_t stream) {
  (void)in_sizes; (void)n_in; (void)out_size;
  const float* v    = (const float*)d_in[0];
  const float* h0   = (const float*)d_in[1];
  const float* Vv   = (const float*)d_in[2];
  const float* Wp   = (const float*)d_in[3];
  const float* Wp_  = (const float*)d_in[4];
  const float* w_ih = (const float*)d_in[5];
  const float* w_hh = (const float*)d_in[6];
  const float* b_ih = (const float*)d_in[7];
  const float* b_hh = (const float*)d_in[8];
  float* out = (float*)d_out;

  // workspace layout; full-tq path needs ~120.2 MiB, chunked ~78.2 MiB
  const bool full_tq = ws_size >= (size_t)125927500;
  float* ws   = (float*)d_ws;
  float* tk   = ws;                                  // 12,582,912 fl
  float* tqF  = tk + (size_t)12582912;               // full path only
  float* tq_c = tk + (size_t)12582912;               // chunked path only
  float* C_c  = full_tq ? (tqF + (size_t)12582912) : (tq_c + (size_t)1572864);
  float* Gi_c = C_c + (size_t)1572864;               // 4,718,592 fl
  float* hb0  = Gi_c + (size_t)4718592;              // 12,288 fl
  float* hb1  = hb0 + (size_t)12288;                 // 12,288 fl
  unsigned* flags = (unsigned*)(hb1 + (size_t)12288); // 24*8*32 u32 = 24 KiB

  // step flags are monotone across the 8 GRU launches: one reset per call
  hipMemsetAsync(flags, 0, (size_t)24 * 8 * GRU_FLAG_STRIDE * sizeof(unsigned), stream);

  // key projection (full): tk = tanh(v . Wp_^T)
  gemm_abt_kernel<<<dim3(4, 192), 256, 0, stream>>>(v, Wp_, tk, 512, 512, nullptr, 1);
  if (full_tq)
    gemm_abt_kernel<<<dim3(4, 192), 256, 0, stream>>>(v, Wp, tqF, 512, 512, nullptr, 1);

  for (int c = 0; c < 8; ++c) {
    const float* v_chunk = v + (size_t)c * 128 * 24 * 512;
    const float* tq_use;
    if (full_tq) {
      tq_use = tqF + (size_t)c * 128 * 24 * 512;
    } else {
      gemm_abt_kernel<<<dim3(4, 24), 256, 0, stream>>>(v_chunk, Wp, tq_c, 512, 512, nullptr, 1);
      tq_use = tq_c;
    }
    attn_kernel<<<dim3(32, 24), 256, 0, stream>>>(tq_use, tk, Vv, v, C_c);
    gemm_abt_kernel<<<dim3(12, 24), 256, 0, stream>>>(C_c, w_ih, Gi_c, 512, 1536, b_ih, 0);
    gru_persist_kernel<<<192, 512, 0, stream>>>(Gi_c, w_hh, b_hh, h0, hb0, hb1,
                                                out, flags, c * 128);
  }
}